// Round 1
// baseline (1627.179 us; speedup 1.0000x reference)
//
#include <hip/hip_runtime.h>

// Correlation layer: out[b, di*9+dj, h, w] = (1/64) * sum_c x1[b,c,h,w] * x2p[b,c,h+di,w+dj]
// x2p = x2 zero-padded by 4 each spatial side. Shapes: B=8, C=64, H=W=192.
//
// v2 (latency/occupancy rework):
//  - LDS 56KB -> 30KB (CK 16->8, x1 row stride padded 32->40): ~1-2 -> 3 blocks/CU (27 waves).
//  - x1 LDS stride 40 (== x2 stride, == 8 mod 32) kills the 4-way bank conflict that the
//    stride-32 x1 tile caused (1.59e7 conflict cycles in v1).
//  - Staging is pure float4 reg-staging: per-thread global offsets, LDS offsets and
//    zero-pad masks are precomputed ONCE in the prologue (clamped addresses + select,
//    no div/mod/branches in the hot loop); per chunk we only add a constant.
//  - Loads for chunk k+1 issue right after compute of chunk k -> latency overlaps the
//    barrier wait and the other resident blocks' compute. Staged regs are dead during
//    compute, keeping peak VGPR under the 7-waves/SIMD cap.

constexpr int MAXD = 4;
constexpr int OD   = 9;    // 2*MAXD+1
constexpr int ND   = 81;   // OD*OD
constexpr int TB_W = 32;   // tile width (pixels)
constexpr int TB_H = 8;    // tile height
constexpr int CK   = 8;    // channels per LDS chunk
constexpr int X2W  = 40;   // TB_W + 2*MAXD
constexpr int X2H  = 16;   // TB_H + 2*MAXD
constexpr int S1W  = 40;   // padded x1 row stride (bank-friendly: 40 % 32 == 8)
constexpr int NT   = 576;  // 9 waves

constexpr int Bc = 8, Cc = 64, Hc = 192, Wc = 192;
constexpr int HW = Hc * Wc;
constexpr int NCHUNK = Cc / CK;        // 8
constexpr int CSTEP  = CK * HW;        // float-offset advance per chunk
constexpr int NF4_X2 = CK * X2H * X2W / 4;   // 1280 float4 per x2 chunk

__global__ __launch_bounds__(NT, 7) void corr_kernel(
    const float* __restrict__ x1, const float* __restrict__ x2,
    float* __restrict__ out)
{
    __shared__ __align__(16) float s1[CK * TB_H * S1W];   // 10240 B
    __shared__ __align__(16) float s2[CK * X2H * X2W];    // 20480 B

    const int tid = threadIdx.x;
    const int g   = tid & 63;
    const int di  = tid >> 6;        // 0..8, wave-uniform
    const int gw4 = (g & 7) * 4;     // 0..28
    const int gh  = g >> 3;          // 0..7

    const int w0 = blockIdx.x * TB_W;
    const int h0 = blockIdx.y * TB_H;
    const int b  = blockIdx.z;

    const float* x1b = x1 + (long)b * Cc * HW;
    const float* x2b = x2 + (long)b * Cc * HW;

    // ---------------- prologue: precompute staging slots ----------------
    // x1: 512 float4 per chunk -> threads 0..511, one float4 each, always in-bounds.
    const bool a1 = (tid < 512);
    int poff, l1o;
    {
        int t  = a1 ? tid : 0;               // dummy slot for inactive threads
        int c  = t >> 6;
        int r  = t & 63;
        int y  = r >> 3;
        int x4 = r & 7;
        poff = c * HW + (h0 + y) * Wc + (w0 + x4 * 4);
        l1o  = c * (TB_H * S1W) + y * S1W + x4 * 4;
    }

    // x2: 1280 float4 per chunk -> 2 per thread + threads 0..127 take a third.
    const bool act2 = (tid < NF4_X2 - 2 * NT);   // tid < 128
    int qoff[3], l2o[3];
    bool mval[3];
#pragma unroll
    for (int i = 0; i < 3; ++i) {
        int idx = tid + i * NT;
        if (idx >= NF4_X2) idx = 0;          // dummy for inactive (i==2, tid>=128)
        int c  = idx / (X2H * X2W / 4);      // /160
        int r  = idx - c * (X2H * X2W / 4);
        int y  = r / (X2W / 4);              // /10
        int x4 = r - y * (X2W / 4);
        int gy = h0 + y - MAXD;              // may be OOB (halo)
        int gx = w0 + x4 * 4 - MAXD;         // f4-aligned: pad==4 -> whole f4 valid or pad
        mval[i] = ((unsigned)gy < (unsigned)Hc) && ((unsigned)gx < (unsigned)Wc);
        int gyc = min(max(gy, 0), Hc - 1);   // clamped address: always safe to load
        int gxc = min(max(gx, 0), Wc - 4);
        qoff[i] = c * HW + gyc * Wc + gxc;
        l2o[i]  = c * (X2H * X2W) + y * X2W + x4 * 4;
    }

    float acc[OD][4];
#pragma unroll
    for (int dj = 0; dj < OD; ++dj)
#pragma unroll
        for (int p = 0; p < 4; ++p) acc[dj][p] = 0.f;

    // initial loads (chunk 0)
    float4 v1 = *(const float4*)(x1b + poff);
    float4 u0 = *(const float4*)(x2b + qoff[0]);
    float4 u1 = *(const float4*)(x2b + qoff[1]);
    float4 u2 = *(const float4*)(x2b + qoff[2]);

#pragma unroll 1
    for (int k = 0; k < NCHUNK; ++k) {
        __syncthreads();   // all waves done computing chunk k-1

        // commit staged regs to LDS (select zero for pad region)
        if (a1) *(float4*)(s1 + l1o) = v1;
        {
            float4 z; z.x = z.y = z.z = z.w = 0.f;
            float4 w0v = mval[0] ? u0 : z;
            float4 w1v = mval[1] ? u1 : z;
            *(float4*)(s2 + l2o[0]) = w0v;
            *(float4*)(s2 + l2o[1]) = w1v;
            if (act2) {
                float4 w2v = mval[2] ? u2 : z;
                *(float4*)(s2 + l2o[2]) = w2v;
            }
        }
        __syncthreads();   // LDS tile ready

        // ---- compute chunk k: per channel 4x ds_read_b128 -> 36 FMAs
#pragma unroll
        for (int c = 0; c < CK; ++c) {
            float4 a = *(const float4*)(s1 + c * (TB_H * S1W) + gh * S1W + gw4);
            const float* wr = s2 + c * (X2H * X2W) + (gh + di) * X2W + gw4;
            float4 b0 = *(const float4*)(wr);
            float4 b1 = *(const float4*)(wr + 4);
            float4 b2 = *(const float4*)(wr + 8);
            float win[12] = {b0.x, b0.y, b0.z, b0.w,
                             b1.x, b1.y, b1.z, b1.w,
                             b2.x, b2.y, b2.z, b2.w};
            float av[4] = {a.x, a.y, a.z, a.w};
#pragma unroll
            for (int dj = 0; dj < OD; ++dj)
#pragma unroll
                for (int p = 0; p < 4; ++p)
                    acc[dj][p] = fmaf(av[p], win[dj + p], acc[dj][p]);
        }

        // ---- issue loads for chunk k+1 (consumed after next barrier; latency
        //      overlaps barrier wait + other blocks' compute)
        if (k + 1 < NCHUNK) {
            poff    += CSTEP;
            qoff[0] += CSTEP;
            qoff[1] += CSTEP;
            qoff[2] += CSTEP;
            v1 = *(const float4*)(x1b + poff);
            u0 = *(const float4*)(x2b + qoff[0]);
            u1 = *(const float4*)(x2b + qoff[1]);
            u2 = *(const float4*)(x2b + qoff[2]);
        }
    }

    // ---- epilogue: 9 float4 stores per thread (mean over C=64)
    const float scale = 1.0f / 64.0f;
    float* ob = out + (((long)b * ND + di * OD) * Hc + (h0 + gh)) * Wc + (w0 + gw4);
#pragma unroll
    for (int dj = 0; dj < OD; ++dj) {
        float4 o;
        o.x = acc[dj][0] * scale;
        o.y = acc[dj][1] * scale;
        o.z = acc[dj][2] * scale;
        o.w = acc[dj][3] * scale;
        *(float4*)(ob + (long)dj * HW) = o;
    }
}

extern "C" void kernel_launch(void* const* d_in, const int* in_sizes, int n_in,
                              void* d_out, int out_size, void* d_ws, size_t ws_size,
                              hipStream_t stream) {
    const float* x1 = (const float*)d_in[0];
    const float* x2 = (const float*)d_in[1];
    float* out = (float*)d_out;
    dim3 grid(Wc / TB_W, Hc / TB_H, Bc);  // (6, 24, 8) = 1152 blocks
    corr_kernel<<<grid, NT, 0, stream>>>(x1, x2, out);
}

// Round 2
// 788.272 us; speedup vs baseline: 2.0642x; 2.0642x over previous
//
#include <hip/hip_runtime.h>

// Correlation: out[b, di*9+dj, h, w] = (1/64) * sum_c x1[b,c,h,w] * x2p[b,c,h+di,w+dj]
// x2p = x2 zero-padded by 4 each side. B=8, C=64, H=W=192.
//
// v3:
//  - FIX of v2's disaster: launch_bounds min-waves 7 capped VGPRs at 256/7=36 -> acc
//    spilled to scratch -> 6 GB HBM traffic. Now (576,4) -> cap 64 (v1's natural count).
//  - x1 is NOT staged in LDS: each thread's x1 float4 is identical across the block's
//    9 waves -> global load hits L1/L2. Removes 1/4 of ds_read_b128 (LDS-pipe floor
//    52us -> 39us), removes x1 staging writes + its bank conflicts, LDS 30KB -> 20KB.
//  - x2-only LDS tile (stride 40 = 8 mod 32: row phases {0,8,16,24} -> 2-way alias,
//    free per m136). Staging writes are address-sequential -> conflict-free.
//  - Halo zero slots are chunk-invariant -> pre-zeroed ONCE in prologue; hot loop has
//    no masks/selects, OOB threads simply skip their load+store.
//  - x2 reg-prefetch for chunk k+1 issued AFTER compute of chunk k (staged regs never
//    overlap compute temps -> peak pressure ~62 < 64).

constexpr int MAXD = 4;
constexpr int OD   = 9;
constexpr int ND   = 81;
constexpr int TB_W = 32;
constexpr int TB_H = 8;
constexpr int CK   = 8;     // channels per LDS chunk
constexpr int X2W  = 40;    // TB_W + 2*MAXD
constexpr int X2H  = 16;    // TB_H + 2*MAXD
constexpr int NT   = 576;   // 9 waves

constexpr int Bc = 8, Cc = 64, Hc = 192, Wc = 192;
constexpr int HW = Hc * Wc;
constexpr int NCHUNK = Cc / CK;              // 8
constexpr int CSTEP  = CK * HW;              // float-offset advance per chunk
constexpr int NF4    = CK * X2H * X2W / 4;   // 1280 float4 per x2 chunk

__global__ __launch_bounds__(NT, 4) void corr_kernel(
    const float* __restrict__ x1, const float* __restrict__ x2,
    float* __restrict__ out)
{
    __shared__ __align__(16) float s2[CK * X2H * X2W];   // 20 KB

    const int tid = threadIdx.x;
    const int g   = tid & 63;
    const int di  = tid >> 6;        // 0..8, wave-uniform
    const int gw4 = (g & 7) * 4;     // 0..28
    const int gh  = g >> 3;          // 0..7

    const int w0 = blockIdx.x * TB_W;
    const int h0 = blockIdx.y * TB_H;
    const int b  = blockIdx.z;

    const float* x1b = x1 + (long)b * Cc * HW;
    const float* x2b = x2 + (long)b * Cc * HW;

    // ---------------- prologue: x2 staging slots (computed once) ----------------
    // 1280 float4 per chunk -> 2 per thread + threads 0..127 take a third.
    int q[3], o[3];
    bool st[3];
#pragma unroll
    for (int i = 0; i < 3; ++i) {
        int idx = tid + i * NT;
        const bool act = (idx < NF4);
        if (!act) idx = 0;
        int c  = idx / (X2H * X2W / 4);      // /160
        int r  = idx - c * (X2H * X2W / 4);
        int y  = r / (X2W / 4);              // /10
        int x4 = r - y * (X2W / 4);
        int gy = h0 + y - MAXD;
        int gx = w0 + x4 * 4 - MAXD;         // f4-aligned; pad=4 -> f4 fully in or out
        const bool inb = ((unsigned)gy < (unsigned)Hc) && ((unsigned)gx < (unsigned)Wc);
        st[i] = act && inb;
        o[i]  = c * (X2H * X2W) + y * X2W + x4 * 4;
        q[i]  = c * HW + gy * Wc + gx;       // only dereferenced when st[i]
        if (act && !inb) {                   // zero-pad slot: chunk-invariant, write once
            float4 z; z.x = z.y = z.z = z.w = 0.f;
            *(float4*)(s2 + o[i]) = z;
        }
    }

    float acc[OD][4];
#pragma unroll
    for (int dj = 0; dj < OD; ++dj)
#pragma unroll
        for (int p = 0; p < 4; ++p) acc[dj][p] = 0.f;

    // x1 channel-stream offset for this thread's own pixels (shared by 9 waves via L1/L2)
    int poff = (h0 + gh) * Wc + (w0 + gw4);

    // LDS read base for compute (bytes folded by compiler; c*640 becomes imm offset)
    const int roff = (gh + di) * X2W + gw4;

    // chunk-0 x2 loads
    float4 u0, u1, u2;
    if (st[0]) u0 = *(const float4*)(x2b + q[0]);
    if (st[1]) u1 = *(const float4*)(x2b + q[1]);
    if (st[2]) u2 = *(const float4*)(x2b + q[2]);

#pragma unroll 1
    for (int k = 0; k < NCHUNK; ++k) {
        __syncthreads();   // previous chunk's LDS reads done (and prologue pre-zero on k=0)
        if (st[0]) *(float4*)(s2 + o[0]) = u0;
        if (st[1]) *(float4*)(s2 + o[1]) = u1;
        if (st[2]) *(float4*)(s2 + o[2]) = u2;
        __syncthreads();   // tile ready

        // ---- compute: per channel 1 global f4 (x1, L1-broadcast across 9 waves)
        //      + 3 ds_read_b128 (x2 window) -> 36 FMAs
#pragma unroll
        for (int c = 0; c < CK; ++c) {
            float4 a = *(const float4*)(x1b + poff);
            poff += HW;
            const float* wr = s2 + c * (X2H * X2W) + roff;
            float4 b0 = *(const float4*)(wr);
            float4 b1 = *(const float4*)(wr + 4);
            float4 b2 = *(const float4*)(wr + 8);
            float win[12] = {b0.x, b0.y, b0.z, b0.w,
                             b1.x, b1.y, b1.z, b1.w,
                             b2.x, b2.y, b2.z, b2.w};
            float av[4] = {a.x, a.y, a.z, a.w};
#pragma unroll
            for (int dj = 0; dj < OD; ++dj)
#pragma unroll
                for (int p = 0; p < 4; ++p)
                    acc[dj][p] = fmaf(av[p], win[dj + p], acc[dj][p]);
        }

        // ---- issue x2 loads for chunk k+1 (latency hides under barrier wait +
        //      other resident blocks' compute; staged regs dead during compute)
        if (k + 1 < NCHUNK) {
            q[0] += CSTEP; q[1] += CSTEP; q[2] += CSTEP;
            if (st[0]) u0 = *(const float4*)(x2b + q[0]);
            if (st[1]) u1 = *(const float4*)(x2b + q[1]);
            if (st[2]) u2 = *(const float4*)(x2b + q[2]);
        }
    }

    // ---- epilogue: 9 float4 stores per thread (mean over C=64)
    const float scale = 1.0f / 64.0f;
    float* ob = out + (((long)b * ND + di * OD) * Hc + (h0 + gh)) * Wc + (w0 + gw4);
#pragma unroll
    for (int dj = 0; dj < OD; ++dj) {
        float4 v;
        v.x = acc[dj][0] * scale;
        v.y = acc[dj][1] * scale;
        v.z = acc[dj][2] * scale;
        v.w = acc[dj][3] * scale;
        *(float4*)(ob + (long)dj * HW) = v;
    }
}

extern "C" void kernel_launch(void* const* d_in, const int* in_sizes, int n_in,
                              void* d_out, int out_size, void* d_ws, size_t ws_size,
                              hipStream_t stream) {
    const float* x1 = (const float*)d_in[0];
    const float* x2 = (const float*)d_in[1];
    float* out = (float*)d_out;
    dim3 grid(Wc / TB_W, Hc / TB_H, Bc);  // (6, 24, 8) = 1152 blocks
    corr_kernel<<<grid, NT, 0, stream>>>(x1, x2, out);
}

// Round 4
// 282.887 us; speedup vs baseline: 5.7520x; 2.7865x over previous
//
#include <hip/hip_runtime.h>

// Correlation: out[b, di*9+dj, h, w] = (1/64) * sum_c x1[b,c,h,w] * x2p[b,c,h+di,w+dj]
// x2p = x2 zero-padded by 4 each side. B=8, C=64, H=W=192.
//
// v5 (v4 + exec-mask fix):
//  - v4 FAILED because global_load_lds writes LDS at wave-uniform-base + lane*16; the
//    per-lane `if (st)` guards made border-block waves partially active -> shifted LDS
//    base -> corrupted halo tiles. v5 keeps ALL lanes active for slots 0/1 and uses a
//    wave-uniform guard (tid<128) for slot 2. Pad lanes redirect their GLOBAL source
//    (per-lane, allowed) to a zero-initialized __device__ 16B page -> pad slots get
//    real zeros each chunk; no pre-zero pass, no divergent exec.
//  - Everything else as v4: x2 staged via global_load_lds (zero staging VGPRs, no
//    ds_writes), double-buffered LDS 2x20KB (3 blocks/CU, 27 waves), ONE barrier per
//    chunk, stage(k+1) issued before compute(k) so HBM latency hides under 288 FMAs,
//    x1 read from global per channel (L1 broadcast across the block's 9 waves).
//  - Spill canary: WRITE_SIZE must be ~93MB (output only). v2/v3 regressions were both
//    accumulator spills (launch_bounds cap 36 / persistent-reg overflow of the 64 cap).

constexpr int MAXD = 4;
constexpr int OD   = 9;
constexpr int ND   = 81;
constexpr int TB_W = 32;
constexpr int TB_H = 8;
constexpr int CK   = 8;     // channels per LDS chunk
constexpr int X2W  = 40;    // TB_W + 2*MAXD
constexpr int X2H  = 16;    // TB_H + 2*MAXD
constexpr int NT   = 576;   // 9 waves

constexpr int Bc = 8, Cc = 64, Hc = 192, Wc = 192;
constexpr int HW = Hc * Wc;
constexpr int NCHUNK = Cc / CK;            // 8
constexpr int CSTEP  = CK * HW;            // float advance per chunk
constexpr int TILE_F = CK * X2H * X2W;     // 5120 floats per buffer
constexpr int NF4    = TILE_F / 4;         // 1280 float4 slots per chunk

// 16B of guaranteed zeros (device globals are zero-initialized; never written).
__device__ __align__(16) float g_zero4[4];

__device__ inline void gload_lds16(const float* g, float* l) {
    __builtin_amdgcn_global_load_lds(
        (const __attribute__((address_space(1))) void*)g,
        (__attribute__((address_space(3))) void*)l, 16, 0, 0);
}

__global__ __launch_bounds__(NT, 4) void corr_kernel(
    const float* __restrict__ x1, const float* __restrict__ x2,
    float* __restrict__ out)
{
    __shared__ __align__(16) float s2[2][TILE_F];   // 2 x 20 KB

    const int tid = threadIdx.x;
    const int g   = tid & 63;
    const int di  = tid >> 6;        // 0..8, wave-uniform
    const int gw4 = (g & 7) * 4;     // 0..28
    const int gh  = g >> 3;          // 0..7

    const int w0 = blockIdx.x * TB_W;
    const int h0 = blockIdx.y * TB_H;
    const int b  = blockIdx.z;

    const float* x1b = x1 + (long)b * Cc * HW;
    const float* x2b = x2 + (long)b * Cc * HW;

    // ---------------- prologue: staging slot geometry (once) ----------------
    // 1280 f4 slots/chunk: i=0,1 -> all 576 threads; i=2 -> threads 0..127 (waves 0-1,
    // fully active => wave-uniform guard, safe for gload_lds).
    int  q0, q1, q2;      // per-thread global float offsets (chunk 0)
    bool st0, st1, st2;   // slot is in-bounds (else source = zero page)
    {
        auto slot = [&](int i, int& q, bool& st) {
            int idx = tid + i * NT;
            if (idx >= NF4) idx = 0;            // only happens under the uniform guard
            int c  = idx / (NF4 / CK);          // /160
            int r  = idx - c * (NF4 / CK);
            int y  = r / (X2W / 4);             // /10
            int x4 = r - y * (X2W / 4);
            int gy = h0 + y - MAXD;
            int gx = w0 + x4 * 4 - MAXD;        // f4-aligned: fully in or fully pad
            st = ((unsigned)gy < (unsigned)Hc) && ((unsigned)gx < (unsigned)Wc);
            q  = c * HW + gy * Wc + gx;         // only dereferenced when st
        };
        slot(0, q0, st0);
        slot(1, q1, st1);
        slot(2, q2, st2);
    }

    float acc[OD][4];
#pragma unroll
    for (int dj = 0; dj < OD; ++dj)
#pragma unroll
        for (int p = 0; p < 4; ++p) acc[dj][p] = 0.f;

    // x1 channel-stream offset (this thread's 4 pixels; L1 broadcast across 9 waves)
    int poff = (h0 + gh) * Wc + (w0 + gw4);
    // LDS read base within a buffer
    const int roff = (gh + di) * X2W + gw4;

    // stage chunk k into buf: all lanes issue; pad lanes read the zero page.
    auto stage = [&](int k, float* buf) {
        const int cb = k * CSTEP;
        float* d = buf + (unsigned)tid * 4;
        const float* z = g_zero4;
        gload_lds16(st0 ? x2b + cb + q0 : z, d);
        gload_lds16(st1 ? x2b + cb + q1 : z, d + NT * 4);
        if (tid < 2 * 64) {   // wave-uniform: waves 0,1 fully active
            gload_lds16(st2 ? x2b + cb + q2 : z, d + 2 * NT * 4);
        }
    };

    // prologue: chunk 0 into buffer 0
    stage(0, s2[0]);
    __syncthreads();   // implicit vmcnt(0) drain, then barrier

#pragma unroll 1
    for (int k = 0; k < NCHUNK; ++k) {
        float* bufA = s2[k & 1];          // compute source (staged last iter)
        float* bufB = s2[(k & 1) ^ 1];    // stage dest (fully consumed last iter)

        // issue next chunk's loads first: latency hides under this chunk's FMAs
        if (k + 1 < NCHUNK) stage(k + 1, bufB);

        // ---- compute: per channel 1 global f4 (x1) + 3 ds_read_b128 (x2) -> 36 FMAs
#pragma unroll
        for (int c = 0; c < CK; ++c) {
            float4 a = *(const float4*)(x1b + poff);
            poff += HW;
            const float* wr = bufA + c * (X2H * X2W) + roff;
            float4 b0 = *(const float4*)(wr);
            float4 b1 = *(const float4*)(wr + 4);
            float4 b2 = *(const float4*)(wr + 8);
            float win[12] = {b0.x, b0.y, b0.z, b0.w,
                             b1.x, b1.y, b1.z, b1.w,
                             b2.x, b2.y, b2.z, b2.w};
            float av[4] = {a.x, a.y, a.z, a.w};
#pragma unroll
            for (int dj = 0; dj < OD; ++dj)
#pragma unroll
                for (int p = 0; p < 4; ++p)
                    acc[dj][p] = fmaf(av[p], win[dj + p], acc[dj][p]);
        }

        __syncthreads();   // drains gload_lds (vmcnt) -> bufB ready for k+1
    }

    // ---- epilogue: 9 float4 stores per thread (mean over C=64)
    const float scale = 1.0f / 64.0f;
    float* ob = out + (((long)b * ND + di * OD) * Hc + (h0 + gh)) * Wc + (w0 + gw4);
#pragma unroll
    for (int dj = 0; dj < OD; ++dj) {
        float4 v;
        v.x = acc[dj][0] * scale;
        v.y = acc[dj][1] * scale;
        v.z = acc[dj][2] * scale;
        v.w = acc[dj][3] * scale;
        *(float4*)(ob + (long)dj * HW) = v;
    }
}

extern "C" void kernel_launch(void* const* d_in, const int* in_sizes, int n_in,
                              void* d_out, int out_size, void* d_ws, size_t ws_size,
                              hipStream_t stream) {
    const float* x1 = (const float*)d_in[0];
    const float* x2 = (const float*)d_in[1];
    float* out = (float*)d_out;
    dim3 grid(Wc / TB_W, Hc / TB_H, Bc);  // (6, 24, 8) = 1152 blocks
    corr_kernel<<<grid, NT, 0, stream>>>(x1, x2, out);
}